// Round 2
// baseline (2136.875 us; speedup 1.0000x reference)
//
#include <hip/hip_runtime.h>
#include <hip/hip_bf16.h>

// EdgeBlock: out[E,64] = relu([edge_attr | x[recv] | x[send] | u] @ W1 + b1) @ W2 + b2
// u folded into b1' by prep. Effective K1 = 192.
//
// R2 changes (theory: gather-path memory pressure):
//  1. x converted to bf16 (xb, 6.4 MB) in prep: node row = one 128B line, halves gather traffic.
//  2. Non-temporal loads on edge_attr, NT stores on out: streams stop evicting xb from L2.
//  3. GEMM2 operands swapped -> D is [out-dim x edge]; lane stores contiguous float4 of its own
//     edge row (full-line write combining). W2^T fragment reads unchanged (A/B layouts mirror).
//  4. Gather software pipeline: indices 2 tiles ahead, gather data 1 tile ahead;
//     __launch_bounds__(1024,4) -> 128 VGPR cap (16 waves/CU, LDS-limited anyway).

#define N_NODES   50000
#define N_EDGES   800000
#define N_TILES   (N_EDGES / 16)
#define K1        192        // D_EDGE + 2*D_NODE (u folded into bias)
#define D_HID     256
#define D_OUT     64
#define W1T_LD    200        // 192 padded
#define W2T_LD    264        // 256 padded
#define WAVES_PB  16
#define BLOCK_T   (WAVES_PB * 64)
#define GRID_MAIN 256

typedef __attribute__((ext_vector_type(8))) short  short8;   // 8 bf16 = one MFMA A/B frag
typedef __attribute__((ext_vector_type(4))) float  floatx4;  // MFMA C/D frag

// workspace layout (bytes)
#define WS_W1T_OFF 0
#define WS_W2T_OFF (256 * W1T_LD * 2)               // 102400
#define WS_B1P_OFF (WS_W2T_OFF + 64 * W2T_LD * 2)   // 136192
#define WS_XB_OFF  (WS_B1P_OFF + 1024)              // 137216; xb = 6.4 MB -> total ~6.54 MB

static __device__ __forceinline__ unsigned short f2bf(float f) {
    unsigned u = __builtin_bit_cast(unsigned, f);
    u += 0x7fffu + ((u >> 16) & 1u);
    return (unsigned short)(u >> 16);
}

static __device__ __forceinline__ short8 pack8(floatx4 f0, floatx4 f1) {
    union { short8 s8; unsigned short us[8]; } u;
    u.us[0] = f2bf(f0.x); u.us[1] = f2bf(f0.y); u.us[2] = f2bf(f0.z); u.us[3] = f2bf(f0.w);
    u.us[4] = f2bf(f1.x); u.us[5] = f2bf(f1.y); u.us[6] = f2bf(f1.z); u.us[7] = f2bf(f1.w);
    return u.s8;
}

static __device__ __forceinline__ short8 cvt8nt(const float* __restrict__ p) {
    const floatx4* p4 = (const floatx4*)p;
    floatx4 f0 = __builtin_nontemporal_load(p4);
    floatx4 f1 = __builtin_nontemporal_load(p4 + 1);
    return pack8(f0, f1);
}

// ---------------- prep: W1^T, W2^T (bf16, padded, W2 rows rho-permuted), b1', xb ----------------
__global__ void edgeblk_prep(const float* __restrict__ W1, const float* __restrict__ b1,
                             const float* __restrict__ W2, const float* __restrict__ u,
                             const float* __restrict__ x,
                             unsigned short* __restrict__ w1t, unsigned short* __restrict__ w2t,
                             float* __restrict__ b1p, unsigned short* __restrict__ xb) {
    int tid = blockIdx.x * blockDim.x + threadIdx.x;
    int nth = gridDim.x * blockDim.x;
    for (int j = tid; j < 256 * K1; j += nth) {        // w1t[n][k] = W1[k][n]
        int n = j / K1, k = j - n * K1;
        w1t[n * W1T_LD + k] = f2bf(W1[k * 256 + n]);
    }
    for (int j = tid; j < 64 * 256; j += nth) {        // w2t[m][k] = W2[perm(k)][m]
        int m = j >> 8, k = j & 255;
        int kap = k & 31, q = kap >> 3, t = kap & 7;
        int rho = (t < 4) ? (q * 4 + t) : (16 + q * 4 + (t - 4));
        int src = (k & ~31) + rho;
        w2t[m * W2T_LD + k] = f2bf(W2[src * 64 + m]);
    }
    for (int n = tid; n < 256; n += nth) {
        float s = b1[n];
        for (int t = 0; t < 16; ++t) s += u[t] * W1[(K1 + t) * 256 + n];
        b1p[n] = s;
    }
    // xb[node][64] bf16 (row = 128B = one cache line)
    short8* xb8 = (short8*)xb;
    for (int j = tid; j < N_NODES * 64 / 8; j += nth) {
        const floatx4* p4 = (const floatx4*)(x + j * 8);
        xb8[j] = pack8(p4[0], p4[1]);
    }
}

// ---------------- main fused kernel ----------------
__global__ __launch_bounds__(BLOCK_T, 4) void edgeblk_mlp(
        const unsigned short* __restrict__ xb, const float* __restrict__ edge_attr,
        const int* __restrict__ eidx,
        const unsigned short* __restrict__ w1t_g, const unsigned short* __restrict__ w2t_g,
        const float* __restrict__ b1p_g, const float* __restrict__ b2_g,
        float* __restrict__ out) {
    // LDS total: 102400 + 33792 + 1024 + 256 = 137,472 B (<= 160 KiB)
    __shared__ alignas(16) unsigned short sW1[256 * W1T_LD];
    __shared__ alignas(16) unsigned short sW2[64 * W2T_LD];
    __shared__ alignas(16) float sB1[256];
    __shared__ alignas(16) float sB2[64];

    {
        const uint4* s1 = (const uint4*)w1t_g;  uint4* d1 = (uint4*)sW1;
        for (int i = threadIdx.x; i < 256 * W1T_LD / 8; i += BLOCK_T) d1[i] = s1[i];
        const uint4* s2 = (const uint4*)w2t_g;  uint4* d2 = (uint4*)sW2;
        for (int i = threadIdx.x; i < 64 * W2T_LD / 8; i += BLOCK_T) d2[i] = s2[i];
        if (threadIdx.x < 256) sB1[threadIdx.x] = b1p_g[threadIdx.x];
        if (threadIdx.x < 64)  sB2[threadIdx.x] = b2_g[threadIdx.x];
    }
    __syncthreads();

    const int wid  = threadIdx.x >> 6;
    const int lane = threadIdx.x & 63;
    const int m    = lane & 15;      // edge-in-tile / B-col / A-row index
    const int quad = lane >> 4;      // k-group (A/B) or row-group (C/D)

    const int gw = blockIdx.x * WAVES_PB + wid;
    const int NW = GRID_MAIN * WAVES_PB;

    // ---- software pipeline: idx 2 ahead, gather data 1 ahead ----
    int tile = gw;
    short8 Rp0 = {}, Rp1 = {}, Sp0 = {}, Sp1 = {};
    int rcv1 = 0, snd1 = 0;
    if (tile < N_TILES) {
        int e = tile * 16 + m;
        int rcv = eidx[N_EDGES + e];
        int snd = eidx[e];
        const short8* pr = (const short8*)(xb + (long)rcv * 64 + quad * 8);
        Rp0 = pr[0]; Rp1 = pr[4];
        const short8* ps = (const short8*)(xb + (long)snd * 64 + quad * 8);
        Sp0 = ps[0]; Sp1 = ps[4];
    }
    if (tile + NW < N_TILES) {
        int e = (tile + NW) * 16 + m;
        rcv1 = eidx[N_EDGES + e];
        snd1 = eidx[e];
    }

    for (; tile < N_TILES; tile += NW) {
        // current-tile fragments
        short8 A[6];
        A[2] = Rp0; A[3] = Rp1; A[4] = Sp0; A[5] = Sp1;
        const float* pe = edge_attr + (long)(tile * 16 + m) * 64 + quad * 8;
        A[0] = cvt8nt(pe);
        A[1] = cvt8nt(pe + 32);

        // issue next tile's gathers; prefetch indices two tiles ahead
        {
            int tn = tile + NW;
            if (tn < N_TILES) {
                const short8* pr = (const short8*)(xb + (long)rcv1 * 64 + quad * 8);
                Rp0 = pr[0]; Rp1 = pr[4];
                const short8* ps = (const short8*)(xb + (long)snd1 * 64 + quad * 8);
                Sp0 = ps[0]; Sp1 = ps[4];
                int t2 = tn + NW;
                if (t2 < N_TILES) {
                    int e2 = t2 * 16 + m;
                    rcv1 = eidx[N_EDGES + e2];
                    snd1 = eidx[e2];
                }
            }
        }

        floatx4 oacc[4];
#pragma unroll
        for (int nt = 0; nt < 4; ++nt) oacc[nt] = (floatx4){0.f, 0.f, 0.f, 0.f};

#pragma unroll
        for (int nc = 0; nc < 8; ++nc) {          // 32-wide chunk of the 256 hidden cols
            floatx4 c0 = (floatx4){0.f, 0.f, 0.f, 0.f};
            floatx4 c1 = (floatx4){0.f, 0.f, 0.f, 0.f};
#pragma unroll
            for (int kt = 0; kt < 6; ++kt) {      // K1 = 192 = 6*32
                short8 bA = *(const short8*)&sW1[(nc * 32      + m) * W1T_LD + kt * 32 + quad * 8];
                short8 bB = *(const short8*)&sW1[(nc * 32 + 16 + m) * W1T_LD + kt * 32 + quad * 8];
                // swapped GEMM1: D = W1chunk . collected^T -> lane m holds edge m
                c0 = __builtin_amdgcn_mfma_f32_16x16x32_bf16(bA, A[kt], c0, 0, 0, 0);
                c1 = __builtin_amdgcn_mfma_f32_16x16x32_bf16(bB, A[kt], c1, 0, 0, 0);
            }
            // bias (broadcast LDS reads) + relu + pack -> GEMM2 fragment, all in registers
            const floatx4 bias0 = *(const floatx4*)&sB1[nc * 32      + quad * 4];
            const floatx4 bias1 = *(const floatx4*)&sB1[nc * 32 + 16 + quad * 4];
            union { short8 s8; unsigned short us[8]; } a2u;
#pragma unroll
            for (int r = 0; r < 4; ++r) {
                float h0 = c0[r] + bias0[r];
                float h1 = c1[r] + bias1[r];
                h0 = h0 > 0.f ? h0 : 0.f;
                h1 = h1 > 0.f ? h1 : 0.f;
                a2u.us[r]     = f2bf(h0);
                a2u.us[r + 4] = f2bf(h1);
            }
            short8 a2 = a2u.s8;
#pragma unroll
            for (int nt = 0; nt < 4; ++nt) {
                short8 b2f = *(const short8*)&sW2[(nt * 16 + m) * W2T_LD + nc * 32 + quad * 8];
                // swapped GEMM2: D = W2chunk . H^T -> lane m holds edge m (col), rows = out-dims
                oacc[nt] = __builtin_amdgcn_mfma_f32_16x16x32_bf16(b2f, a2, oacc[nt], 0, 0, 0);
            }
        }

        // epilogue: lane m owns edge row m; out-dim = nt*16 + quad*4 + r -> contiguous float4
        float* po = out + (long)tile * 16 * 64 + m * 64;
#pragma unroll
        for (int nt = 0; nt < 4; ++nt) {
            const floatx4 bb = *(const floatx4*)&sB2[nt * 16 + quad * 4];
            floatx4 v;
#pragma unroll
            for (int r = 0; r < 4; ++r) v[r] = oacc[nt][r] + bb[r];
            __builtin_nontemporal_store(v, (floatx4*)(po + nt * 16 + quad * 4));
        }
    }
}

extern "C" void kernel_launch(void* const* d_in, const int* in_sizes, int n_in,
                              void* d_out, int out_size, void* d_ws, size_t ws_size,
                              hipStream_t stream) {
    const float* x   = (const float*)d_in[0];
    const float* ea  = (const float*)d_in[1];
    const float* u   = (const float*)d_in[2];
    const float* W1  = (const float*)d_in[3];
    const float* b1  = (const float*)d_in[4];
    const float* W2  = (const float*)d_in[5];
    const float* b2  = (const float*)d_in[6];
    const int*   ei  = (const int*)d_in[7];
    float* out = (float*)d_out;

    unsigned short* w1t = (unsigned short*)((char*)d_ws + WS_W1T_OFF);
    unsigned short* w2t = (unsigned short*)((char*)d_ws + WS_W2T_OFF);
    float*          b1p = (float*)((char*)d_ws + WS_B1P_OFF);
    unsigned short* xb  = (unsigned short*)((char*)d_ws + WS_XB_OFF);

    hipLaunchKernelGGL(edgeblk_prep, dim3(256), dim3(256), 0, stream,
                       W1, b1, W2, u, x, w1t, w2t, b1p, xb);
    hipLaunchKernelGGL(edgeblk_mlp, dim3(GRID_MAIN), dim3(BLOCK_T), 0, stream,
                       xb, ea, ei, w1t, w2t, b1p, b2, out);
}

// Round 3
// 2022.860 us; speedup vs baseline: 1.0564x; 1.0564x over previous
//
#include <hip/hip_runtime.h>
#include <hip/hip_bf16.h>

// EdgeBlock: out[E,64] = relu([edge_attr | x[recv] | x[send] | u] @ W1 + b1) @ W2 + b2
// u folded into b1' by prep. Effective K1 = 192.
//
// R3 theory: R1/R2's 3.6 GB FETCH / 730-960 MB WRITE was register SPILL traffic —
// compiler pinned at 64 arch-VGPRs (occupancy heuristic ignores the 137 KB LDS that
// already caps us at 1 block/CU = 4 waves/EU), so the A-fragments + bias arrays +
// pipeline regs spilled, and the A-frags were re-FILLED in every nc iteration
// (8 x 96 B/lane/tile ~ the 2.9 GB fetch excess).
// Fixes: amdgpu_waves_per_eu(4,4) -> 128-reg budget; remove software pipeline;
// all biases via LDS broadcast (no per-lane bias register arrays); revert NT ops.
// Keep: bf16 xb gathers, swapped GEMM1/GEMM2 (all-register inter-GEMM transpose),
// contiguous per-lane float4 stores.

#define N_NODES   50000
#define N_EDGES   800000
#define N_TILES   (N_EDGES / 16)
#define K1        192        // D_EDGE + 2*D_NODE (u folded into bias)
#define D_HID     256
#define D_OUT     64
#define W1T_LD    200        // 192 padded: 100 words == 4 mod 32 -> ~2-way (free) frag reads
#define W2T_LD    264        // 256 padded: 132 words == 4 mod 32
#define WAVES_PB  16
#define BLOCK_T   (WAVES_PB * 64)
#define GRID_MAIN 256

typedef __attribute__((ext_vector_type(8))) short  short8;   // 8 bf16 = one MFMA A/B frag
typedef __attribute__((ext_vector_type(4))) float  floatx4;  // MFMA C/D frag

// workspace layout (bytes)
#define WS_W1T_OFF 0
#define WS_W2T_OFF (256 * W1T_LD * 2)               // 102400
#define WS_B1P_OFF (WS_W2T_OFF + 64 * W2T_LD * 2)   // 136192
#define WS_XB_OFF  (WS_B1P_OFF + 1024)              // 137216; xb = 6.4 MB

static __device__ __forceinline__ unsigned short f2bf(float f) {
    unsigned u = __builtin_bit_cast(unsigned, f);
    u += 0x7fffu + ((u >> 16) & 1u);
    return (unsigned short)(u >> 16);
}

static __device__ __forceinline__ short8 pack8(floatx4 f0, floatx4 f1) {
    union { short8 s8; unsigned short us[8]; } u;
    u.us[0] = f2bf(f0.x); u.us[1] = f2bf(f0.y); u.us[2] = f2bf(f0.z); u.us[3] = f2bf(f0.w);
    u.us[4] = f2bf(f1.x); u.us[5] = f2bf(f1.y); u.us[6] = f2bf(f1.z); u.us[7] = f2bf(f1.w);
    return u.s8;
}

static __device__ __forceinline__ short8 cvt8(const float* __restrict__ p) {
    const floatx4* p4 = (const floatx4*)p;
    return pack8(p4[0], p4[1]);
}

// ---------------- prep: W1^T, W2^T (bf16, padded, W2 rows rho-permuted), b1', xb ----------------
__global__ void edgeblk_prep(const float* __restrict__ W1, const float* __restrict__ b1,
                             const float* __restrict__ W2, const float* __restrict__ u,
                             const float* __restrict__ x,
                             unsigned short* __restrict__ w1t, unsigned short* __restrict__ w2t,
                             float* __restrict__ b1p, unsigned short* __restrict__ xb) {
    int tid = blockIdx.x * blockDim.x + threadIdx.x;
    int nth = gridDim.x * blockDim.x;
    for (int j = tid; j < 256 * K1; j += nth) {        // w1t[n][k] = W1[k][n]
        int n = j / K1, k = j - n * K1;
        w1t[n * W1T_LD + k] = f2bf(W1[k * 256 + n]);
    }
    for (int j = tid; j < 64 * 256; j += nth) {        // w2t[m][k] = W2[perm(k)][m]
        int m = j >> 8, k = j & 255;
        int kap = k & 31, q = kap >> 3, t = kap & 7;
        int rho = (t < 4) ? (q * 4 + t) : (16 + q * 4 + (t - 4));
        int src = (k & ~31) + rho;
        w2t[m * W2T_LD + k] = f2bf(W2[src * 64 + m]);
    }
    for (int n = tid; n < 256; n += nth) {
        float s = b1[n];
        for (int t = 0; t < 16; ++t) s += u[t] * W1[(K1 + t) * 256 + n];
        b1p[n] = s;
    }
    // xb[node][64] bf16 (row = 128B = one cache line)
    short8* xb8 = (short8*)xb;
    for (int j = tid; j < N_NODES * 64 / 8; j += nth) {
        const floatx4* p4 = (const floatx4*)(x + j * 8);
        xb8[j] = pack8(p4[0], p4[1]);
    }
}

// ---------------- main fused kernel ----------------
__global__ __launch_bounds__(BLOCK_T)
__attribute__((amdgpu_waves_per_eu(4, 4)))
void edgeblk_mlp(
        const unsigned short* __restrict__ xb, const float* __restrict__ edge_attr,
        const int* __restrict__ eidx,
        const unsigned short* __restrict__ w1t_g, const unsigned short* __restrict__ w2t_g,
        const float* __restrict__ b1p_g, const float* __restrict__ b2_g,
        float* __restrict__ out) {
    // LDS total: 102400 + 33792 + 1024 + 256 = 137,472 B (<= 160 KiB) -> 1 block/CU
    __shared__ alignas(16) unsigned short sW1[256 * W1T_LD];
    __shared__ alignas(16) unsigned short sW2[64 * W2T_LD];
    __shared__ alignas(16) float sB1[256];
    __shared__ alignas(16) float sB2[64];

    {
        const uint4* s1 = (const uint4*)w1t_g;  uint4* d1 = (uint4*)sW1;
        for (int i = threadIdx.x; i < 256 * W1T_LD / 8; i += BLOCK_T) d1[i] = s1[i];
        const uint4* s2 = (const uint4*)w2t_g;  uint4* d2 = (uint4*)sW2;
        for (int i = threadIdx.x; i < 64 * W2T_LD / 8; i += BLOCK_T) d2[i] = s2[i];
        if (threadIdx.x < 256) sB1[threadIdx.x] = b1p_g[threadIdx.x];
        if (threadIdx.x < 64)  sB2[threadIdx.x] = b2_g[threadIdx.x];
    }
    __syncthreads();

    const int wid  = threadIdx.x >> 6;
    const int lane = threadIdx.x & 63;
    const int m    = lane & 15;      // edge-in-tile / B-col index
    const int quad = lane >> 4;      // k-group (A/B) or row-group (C/D)

    const int gw = blockIdx.x * WAVES_PB + wid;
    const int NW = GRID_MAIN * WAVES_PB;

    for (int tile = gw; tile < N_TILES; tile += NW) {
        const int e    = tile * 16 + m;
        const int recv = eidx[N_EDGES + e];   // edge_index[1]
        const int send = eidx[e];             // edge_index[0]

        // frags of collected[16 x 192]: lane holds edge m, k = kt*32+quad*8..+8
        short8 A[6];
        {
            const float* pe = edge_attr + (long)e * 64 + quad * 8;
            A[0] = cvt8(pe);
            A[1] = cvt8(pe + 32);
            const short8* pr = (const short8*)(xb + (long)recv * 64 + quad * 8);
            A[2] = pr[0]; A[3] = pr[4];   // +4*8 shorts = dims 32+quad*8
            const short8* ps = (const short8*)(xb + (long)send * 64 + quad * 8);
            A[4] = ps[0]; A[5] = ps[4];
        }

        floatx4 oacc[4];
#pragma unroll
        for (int nt = 0; nt < 4; ++nt) oacc[nt] = (floatx4){0.f, 0.f, 0.f, 0.f};

#pragma unroll
        for (int nc = 0; nc < 8; ++nc) {          // 32-wide chunk of the 256 hidden cols
            floatx4 c0 = (floatx4){0.f, 0.f, 0.f, 0.f};
            floatx4 c1 = (floatx4){0.f, 0.f, 0.f, 0.f};
#pragma unroll
            for (int kt = 0; kt < 6; ++kt) {      // K1 = 192 = 6*32
                short8 bA = *(const short8*)&sW1[(nc * 32      + m) * W1T_LD + kt * 32 + quad * 8];
                short8 bB = *(const short8*)&sW1[(nc * 32 + 16 + m) * W1T_LD + kt * 32 + quad * 8];
                // swapped GEMM1: D = W1chunk . collected^T -> lane m holds edge m
                c0 = __builtin_amdgcn_mfma_f32_16x16x32_bf16(bA, A[kt], c0, 0, 0, 0);
                c1 = __builtin_amdgcn_mfma_f32_16x16x32_bf16(bB, A[kt], c1, 0, 0, 0);
            }
            // bias (broadcast LDS reads) + relu + pack -> GEMM2 fragment, in registers
            const floatx4 bias0 = *(const floatx4*)&sB1[nc * 32      + quad * 4];
            const floatx4 bias1 = *(const floatx4*)&sB1[nc * 32 + 16 + quad * 4];
            union { short8 s8; unsigned short us[8]; } a2u;
#pragma unroll
            for (int r = 0; r < 4; ++r) {
                float h0 = c0[r] + bias0[r];
                float h1 = c1[r] + bias1[r];
                h0 = h0 > 0.f ? h0 : 0.f;
                h1 = h1 > 0.f ? h1 : 0.f;
                a2u.us[r]     = f2bf(h0);
                a2u.us[r + 4] = f2bf(h1);
            }
            short8 a2 = a2u.s8;
#pragma unroll
            for (int nt = 0; nt < 4; ++nt) {
                short8 b2f = *(const short8*)&sW2[(nt * 16 + m) * W2T_LD + nc * 32 + quad * 8];
                // swapped GEMM2: D = W2chunk . H^T -> lane m holds edge m (col), rows = out-dims
                oacc[nt] = __builtin_amdgcn_mfma_f32_16x16x32_bf16(b2f, a2, oacc[nt], 0, 0, 0);
            }
        }

        // epilogue: lane m owns edge row m; out-dim = nt*16 + quad*4 + r -> contiguous float4
        float* po = out + (long)tile * 16 * 64 + m * 64;
#pragma unroll
        for (int nt = 0; nt < 4; ++nt) {
            const floatx4 bb = *(const floatx4*)&sB2[nt * 16 + quad * 4];
            floatx4 v;
#pragma unroll
            for (int r = 0; r < 4; ++r) v[r] = oacc[nt][r] + bb[r];
            *(floatx4*)(po + nt * 16 + quad * 4) = v;
        }
    }
}

extern "C" void kernel_launch(void* const* d_in, const int* in_sizes, int n_in,
                              void* d_out, int out_size, void* d_ws, size_t ws_size,
                              hipStream_t stream) {
    const float* x   = (const float*)d_in[0];
    const float* ea  = (const float*)d_in[1];
    const float* u   = (const float*)d_in[2];
    const float* W1  = (const float*)d_in[3];
    const float* b1  = (const float*)d_in[4];
    const float* W2  = (const float*)d_in[5];
    const float* b2  = (const float*)d_in[6];
    const int*   ei  = (const int*)d_in[7];
    float* out = (float*)d_out;

    unsigned short* w1t = (unsigned short*)((char*)d_ws + WS_W1T_OFF);
    unsigned short* w2t = (unsigned short*)((char*)d_ws + WS_W2T_OFF);
    float*          b1p = (float*)((char*)d_ws + WS_B1P_OFF);
    unsigned short* xb  = (unsigned short*)((char*)d_ws + WS_XB_OFF);

    hipLaunchKernelGGL(edgeblk_prep, dim3(256), dim3(256), 0, stream,
                       W1, b1, W2, u, x, w1t, w2t, b1p, xb);
    hipLaunchKernelGGL(edgeblk_mlp, dim3(GRID_MAIN), dim3(BLOCK_T), 0, stream,
                       xb, ea, ei, w1t, w2t, b1p, b2, out);
}